// Round 1
// baseline (245.390 us; speedup 1.0000x reference)
//
#include <hip/hip_runtime.h>

// INT4 symmetric weight dequant: packed uint8-in-int32 nibbles -> fp32, per-(row,group) scale.
// OUT=4096, GROUPS=86, GSIZE=128. TOTAL = 45,088,768 elements.
// Memory-bound: ~90 MB in (packed int32) + 1.4 MB scales + 180 MB out fp32.

#define TOTAL_ELEMS (4096 * 86 * 128)      // 45,088,768
#define NPACK (TOTAL_ELEMS / 2)            // 22,544,384 int32 "bytes"
#define NTHREADS (NPACK / 4)               // 5,636,096 (each thread: 4 packed -> 8 floats)

__global__ __launch_bounds__(256) void int4_dequant_kernel(
    const int4* __restrict__ packed,   // NPACK/4 int4 loads
    const float* __restrict__ scale,   // 4096*86 flat, one per 128 output elems
    float4* __restrict__ out)          // TOTAL/4 float4 stores
{
    const int t = blockIdx.x * blockDim.x + threadIdx.x;
    if (t >= NTHREADS) return;

    int4 p = packed[t];                // 4 packed bytes (each in [0,256))
    const int e = t * 8;               // first of 8 consecutive output elements
    const float s = scale[e >> 7];     // all 8 share one (row,group) scale

    float4 o0, o1;
    o0.x = (float)((p.x & 15) - 8) * s;
    o0.y = (float)((p.x >> 4) - 8) * s;
    o0.z = (float)((p.y & 15) - 8) * s;
    o0.w = (float)((p.y >> 4) - 8) * s;
    o1.x = (float)((p.z & 15) - 8) * s;
    o1.y = (float)((p.z >> 4) - 8) * s;
    o1.z = (float)((p.w & 15) - 8) * s;
    o1.w = (float)((p.w >> 4) - 8) * s;

    out[t * 2]     = o0;
    out[t * 2 + 1] = o1;
}

extern "C" void kernel_launch(void* const* d_in, const int* in_sizes, int n_in,
                              void* d_out, int out_size, void* d_ws, size_t ws_size,
                              hipStream_t stream) {
    const int4*  packed = (const int4*)d_in[0];
    const float* scale  = (const float*)d_in[1];
    float4*      out    = (float4*)d_out;

    const int threads = 256;
    const int blocks  = (NTHREADS + threads - 1) / threads;   // 22016 exactly
    int4_dequant_kernel<<<blocks, threads, 0, stream>>>(packed, scale, out);
}

// Round 3
// 235.361 us; speedup vs baseline: 1.0426x; 1.0426x over previous
//
#include <hip/hip_runtime.h>

// INT4 symmetric weight dequant: packed uint8-in-int32 nibbles -> fp32,
// per-(row,group) scale. OUT=4096, GROUPS=86, GSIZE=128.
// TOTAL = 45,088,768 fp32 outputs = 11,272,192 float4 "quads".
// Each quad q needs packed int32s {2q, 2q+1} (one 8B load) and scale[q>>5].
//
// Memory floor: 90 MB packed read + 1.4 MB scale + 180 MB fp32 write = 272 MB
// -> ~42 us at the 6.5 TB/s observed fill ceiling. Strictly memory-bound.
//
// Layout: each thread handles TWO quads, arranged so every memory instruction
// is perfectly contiguous across the wave: lane l of a wave handles quads
// (wave_base + l) and (wave_base + 64 + l). All loads/stores non-temporal
// (pure streaming, no reuse -> don't allocate in L2/LLC).
//
// NOTE: __builtin_nontemporal_* requires clang native vector types, not
// HIP_vector_type structs -> use ext_vector_type typedefs.

#define TOTAL_ELEMS (4096 * 86 * 128)        // 45,088,768
#define NQUADS (TOTAL_ELEMS / 4)             // 11,272,192 float4s
#define NTHREADS (NQUADS / 2)                // 5,636,096
#define NBLOCKS (NTHREADS / 256)             // 22016 exactly

typedef int   v2i __attribute__((ext_vector_type(2)));
typedef float v4f __attribute__((ext_vector_type(4)));

__global__ __launch_bounds__(256) void int4_dequant_kernel(
    const v2i* __restrict__ packed,    // NQUADS 8B chunks (8 nibbles each)
    const float* __restrict__ scale,   // 4096*86 flat, one per 32 quads
    v4f* __restrict__ out)             // NQUADS float4s
{
    const int t = blockIdx.x * 256 + threadIdx.x;
    const int lane = t & 63;
    const int q0 = ((t & ~63) << 1) + lane;  // wave_base*2 + lane
    const int q1 = q0 + 64;

    v2i a = __builtin_nontemporal_load(&packed[q0]);
    v2i b = __builtin_nontemporal_load(&packed[q1]);
    const float s0 = scale[q0 >> 5];
    const float s1 = scale[q1 >> 5];

    v4f o0, o1;
    o0.x = (float)((a.x & 15) - 8) * s0;
    o0.y = (float)((a.x >> 4) - 8) * s0;
    o0.z = (float)((a.y & 15) - 8) * s0;
    o0.w = (float)((a.y >> 4) - 8) * s0;
    o1.x = (float)((b.x & 15) - 8) * s1;
    o1.y = (float)((b.x >> 4) - 8) * s1;
    o1.z = (float)((b.y & 15) - 8) * s1;
    o1.w = (float)((b.y >> 4) - 8) * s1;

    __builtin_nontemporal_store(o0, &out[q0]);
    __builtin_nontemporal_store(o1, &out[q1]);
}

extern "C" void kernel_launch(void* const* d_in, const int* in_sizes, int n_in,
                              void* d_out, int out_size, void* d_ws, size_t ws_size,
                              hipStream_t stream) {
    const v2i*   packed = (const v2i*)d_in[0];
    const float* scale  = (const float*)d_in[1];
    v4f*         out    = (v4f*)d_out;

    int4_dequant_kernel<<<NBLOCKS, 256, 0, stream>>>(packed, scale, out);
}